// Round 5
// baseline (217.901 us; speedup 1.0000x reference)
//
#include <hip/hip_runtime.h>

// out[b,m,f,t] = sum_c W[m,f,c] * x[b,m,c,t]
// x: [B=256][NM=5][NC=64][T=1024] f32, W: [NM=5][NF=40][NC=64] f32
// out: [B][NM][NF=40][T] f32
//
// Memory-bound: ~532 MB @ 6.3-7.0 TB/s => ~80-86 us floor.
// R4: kill the dispatch-tail. 5120 fine-grained blocks (one per quarter
// t-row, 1 float/thread), no software persistent loop (R2's codegen trap).
// acc[40] -> ~80 VGPR -> 5-6 blocks/CU -> tail ~ one block (~5 us), plus
// more waves/CU for latency hiding.

#define B_  256
#define NM_ 5
#define NC_ 64
#define T_  1024
#define NF_ 40
#define QT_ 256       // t's per block
#define CCHUNK 8

__global__ __launch_bounds__(256) void trca_einsum_kernel(
    const float* __restrict__ x,
    const float* __restrict__ W,
    float* __restrict__ out)
{
    const int tile = blockIdx.x;        // 0..5119
    const int q    = tile & 3;          // quarter index within T
    const int bm   = tile >> 2;         // b*NM + m
    const int m    = bm % NM_;
    const int t0   = q * QT_ + threadIdx.x;

    const float* __restrict__ xp = x + (size_t)bm * NC_ * T_ + t0;  // stride T_ per c
    const float* __restrict__ wp = W + (size_t)m * NF_ * NC_;       // W[m,f,c]
    float* __restrict__ op = out + (size_t)bm * NF_ * T_ + t0;      // stride T_ per f

    float acc[NF_];
#pragma unroll
    for (int f = 0; f < NF_; ++f) acc[f] = 0.0f;

#pragma unroll 1
    for (int cc = 0; cc < NC_; cc += CCHUNK) {
        float xv[CCHUNK];
#pragma unroll
        for (int i = 0; i < CCHUNK; ++i) {
            xv[i] = xp[(size_t)(cc + i) * T_];
        }
#pragma unroll
        for (int i = 0; i < CCHUNK; ++i) {
#pragma unroll
            for (int f = 0; f < NF_; ++f) {
                acc[f] += wp[f * NC_ + cc + i] * xv[i];  // w: wave-uniform s_load
            }
        }
    }

#pragma unroll
    for (int f = 0; f < NF_; ++f) {
        __builtin_nontemporal_store(acc[f], op + (size_t)f * T_);
    }
}

extern "C" void kernel_launch(void* const* d_in, const int* in_sizes, int n_in,
                              void* d_out, int out_size, void* d_ws, size_t ws_size,
                              hipStream_t stream)
{
    const float* x = (const float*)d_in[0];
    const float* W = (const float*)d_in[1];
    float* out = (float*)d_out;

    const int grid = B_ * NM_ * (T_ / QT_);   // 5120 blocks
    trca_einsum_kernel<<<grid, 256, 0, stream>>>(x, W, out);
}

// Round 6
// 135.995 us; speedup vs baseline: 1.6023x; 1.6023x over previous
//
#include <hip/hip_runtime.h>

// out[b,m,f,t] = sum_c W[m,f,c] * x[b,m,c,t]
// x: [B=256][NM=5][NC=64][T=1024] f32, W: [NM=5][NF=40][NC=64] f32
// out: [B][NM][NF=40][T] f32
//
// True HBM traffic (measured): ~378 MB (L3 retains ~half of x across
// replays) => floor ~55-60 us @ ~6.9 TB/s measured ceiling.
// R5: kill the dispatch tail EXACTLY. f split in half (acc demand ~56 VGPR,
// far from both the spill cliff and the compiler's squeeze heuristic) and
// 32 KB dynamic-LDS ballast -> hardware-pinned 5 blocks/CU -> 1280
// concurrent blocks; grid 5120 = 4.0 generations, zero tail; 20 waves/CU.

#define B_  256
#define NM_ 5
#define NC_ 64
#define T_  1024
#define NF_ 40
#define FH_ 20        // f's per block
#define CCHUNK 4

__global__ __launch_bounds__(256, 5) void trca_einsum_kernel(
    const float* __restrict__ x,
    const float* __restrict__ W,
    float* __restrict__ out)
{
    // bid: [bm(1280)][thalf(2)][fhalf(2)] ; fhalf fastest so sibling blocks
    // (same x tile) are adjacent -> co-resident -> L3/L2 serve the re-read.
    const int bid   = blockIdx.x;
    const int fhalf = bid & 1;
    const int thalf = (bid >> 1) & 1;
    const int bm    = bid >> 2;          // b*NM + m
    const int m     = bm % NM_;
    const int t0    = thalf * (T_ / 2) + threadIdx.x * 2;

    const float* __restrict__ xp = x + (size_t)bm * NC_ * T_ + t0;   // stride T_ per c
    const float* __restrict__ wp = W + (size_t)m * NF_ * NC_ + (size_t)fhalf * FH_ * NC_;
    float* __restrict__ op = out + (size_t)bm * NF_ * T_ + (size_t)fhalf * FH_ * T_ + t0;

    float acc0[FH_], acc1[FH_];
#pragma unroll
    for (int f = 0; f < FH_; ++f) { acc0[f] = 0.0f; acc1[f] = 0.0f; }

    for (int cc = 0; cc < NC_; cc += CCHUNK) {
        float2 xv[CCHUNK];
#pragma unroll
        for (int i = 0; i < CCHUNK; ++i)
            xv[i] = *reinterpret_cast<const float2*>(xp + (size_t)(cc + i) * T_);
#pragma unroll
        for (int i = 0; i < CCHUNK; ++i) {
#pragma unroll
            for (int f = 0; f < FH_; ++f) {
                const float w = wp[f * NC_ + cc + i];   // wave-uniform -> s_load
                acc0[f] += w * xv[i].x;
                acc1[f] += w * xv[i].y;
            }
        }
    }

#pragma unroll
    for (int f = 0; f < FH_; ++f) {
        __builtin_nontemporal_store(acc0[f], op + (size_t)f * T_);
        __builtin_nontemporal_store(acc1[f], op + (size_t)f * T_ + 1);
    }
}

extern "C" void kernel_launch(void* const* d_in, const int* in_sizes, int n_in,
                              void* d_out, int out_size, void* d_ws, size_t ws_size,
                              hipStream_t stream)
{
    const float* x = (const float*)d_in[0];
    const float* W = (const float*)d_in[1];
    float* out = (float*)d_out;

    const int grid = B_ * NM_ * 2 * 2;   // 5120 blocks (bm x thalf x fhalf)
    // 32 KB dynamic-LDS ballast: pins exactly 5 blocks/CU (160/32), making
    // 1280 concurrent blocks -> grid is exactly 4 generations, zero tail.
    trca_einsum_kernel<<<grid, 256, 32768, stream>>>(x, W, out);
}